// Round 6
// baseline (387.574 us; speedup 1.0000x reference)
//
#include <hip/hip_runtime.h>
#include <math.h>

#define NN 1024   // nodes
#define DD 128    // dim
#define BB 1024   // graphs

typedef float floatx4 __attribute__((ext_vector_type(4)));

__device__ __forceinline__ float waveReduceSum(float v) {
#pragma unroll
  for (int off = 32; off > 0; off >>= 1) v += __shfl_xor(v, off);
  return v;
}
__device__ __forceinline__ float waveReduceMax(float v) {
#pragma unroll
  for (int off = 32; off > 0; off >>= 1) v = fmaxf(v, __shfl_xor(v, off));
  return v;
}

// K1 prep: blocks 0..NN-1 normalize node rows, NN..NN+BB-1 normalize graph
// rows, NN+BB..NN+2*BB-1 compute gm row max/denominator. 64 threads/block.
__global__ __launch_bounds__(64) void prep_kernel(
    const float* __restrict__ ne, const float* __restrict__ ge,
    const float* __restrict__ gm, float* __restrict__ ne_n,
    float* __restrict__ ge_n, float* __restrict__ gm_max,
    float* __restrict__ gm_den) {
  int b = blockIdx.x;
  int lane = threadIdx.x;
  if (b < NN + BB) {
    const float* src;
    float* dst;
    if (b < NN) { src = ne + (size_t)b * DD; dst = ne_n + (size_t)b * DD; }
    else { src = ge + (size_t)(b - NN) * DD; dst = ge_n + (size_t)(b - NN) * DD; }
    float2 v = ((const float2*)src)[lane];
    float ss = v.x * v.x + v.y * v.y;
    ss = waveReduceSum(ss);
    float scale = 1.0f / fmaxf(sqrtf(ss), 1e-12f);
    float2 o;
    o.x = v.x * scale;
    o.y = v.y * scale;
    ((float2*)dst)[lane] = o;
  } else {
    int row = b - (NN + BB);
    const float4* r = (const float4*)(gm + (size_t)row * BB);
    float vals[16];
    float m = -INFINITY;
#pragma unroll
    for (int k = 0; k < 4; ++k) {
      float4 v = r[lane + 64 * k];
      vals[k * 4 + 0] = v.x; vals[k * 4 + 1] = v.y;
      vals[k * 4 + 2] = v.z; vals[k * 4 + 3] = v.w;
      m = fmaxf(m, fmaxf(fmaxf(v.x, v.y), fmaxf(v.z, v.w)));
    }
    m = waveReduceMax(m);
    float s = 0.f;
#pragma unroll
    for (int t = 0; t < 16; ++t) s += expf(vals[t] - m);
    s = waveReduceSum(s);
    if (lane == 0) { gm_max[row] = m; gm_den[row] = s; }
  }
}

// K2 loss: blocks 0..1023 node-loss rows; 1024..2047 graph-loss rows
// (+ graph_logits store). 16-lane group per j-row dot product.
__global__ __launch_bounds__(256) void loss_kernel(
    const float* __restrict__ nen, const float* __restrict__ gen,
    const float* __restrict__ gm, const float* __restrict__ gm_max,
    const float* __restrict__ gm_den, float* __restrict__ out_logits,
    float* __restrict__ node_partial, float* __restrict__ graph_partial) {
  int bid = blockIdx.x;
  int tid = threadIdx.x;
  int lane = tid & 63, wid = tid >> 6;
  int g = lane >> 4, gl = lane & 15;
  __shared__ float q[DD];
  __shared__ float logits[NN];
  __shared__ float red[8];

  if (bid < 1024) {
    int i = bid;
    if (tid < DD) q[tid] = nen[(size_t)i * DD + tid];
    __syncthreads();
    const float4* qv = (const float4*)q;
    float4 b0 = qv[gl * 2], b1 = qv[gl * 2 + 1];
#pragma unroll 4
    for (int p = 0; p < 64; ++p) {
      int j = p * 16 + wid * 4 + g;
      const float4* rowp = (const float4*)(nen + (size_t)j * DD);
      float4 a0 = rowp[gl * 2], a1 = rowp[gl * 2 + 1];
      float acc = a0.x * b0.x + a0.y * b0.y + a0.z * b0.z + a0.w * b0.w +
                  a1.x * b1.x + a1.y * b1.y + a1.z * b1.z + a1.w * b1.w;
      acc += __shfl_xor(acc, 1);
      acc += __shfl_xor(acc, 2);
      acc += __shfl_xor(acc, 4);
      acc += __shfl_xor(acc, 8);
      if (gl == 0) logits[j] = acc;
    }
    __syncthreads();
    float lv[4];
    float m = -INFINITY;
#pragma unroll
    for (int k = 0; k < 4; ++k) {
      lv[k] = logits[tid + 256 * k];
      m = fmaxf(m, lv[k]);
    }
    m = waveReduceMax(m);
    if (lane == 0) red[wid] = m;
    __syncthreads();
    float M = fmaxf(fmaxf(red[0], red[1]), fmaxf(red[2], red[3]));
    float s = 0.f;
#pragma unroll
    for (int k = 0; k < 4; ++k) s += expf(lv[k] - M);
    s = waveReduceSum(s);
    if (lane == 0) red[4 + wid] = s;
    __syncthreads();
    float S = red[4] + red[5] + red[6] + red[7];
    if (tid == 0) node_partial[i] = logits[i] - (M + logf(S));
  } else {
    // graph loss row i. logits matrix symmetric (bitwise: same reduction
    // order) so lpT == lp; fold both loss terms into one weighted sum.
    int i = bid - 1024;
    if (tid < DD) q[tid] = gen[(size_t)i * DD + tid];
    __syncthreads();
    const float4* qv = (const float4*)q;
    float4 b0 = qv[gl * 2], b1 = qv[gl * 2 + 1];
#pragma unroll 4
    for (int p = 0; p < 64; ++p) {
      int j = p * 16 + wid * 4 + g;
      const float4* rowp = (const float4*)(gen + (size_t)j * DD);
      float4 a0 = rowp[gl * 2], a1 = rowp[gl * 2 + 1];
      float acc = a0.x * b0.x + a0.y * b0.y + a0.z * b0.z + a0.w * b0.w +
                  a1.x * b1.x + a1.y * b1.y + a1.z * b1.z + a1.w * b1.w;
      acc += __shfl_xor(acc, 1);
      acc += __shfl_xor(acc, 2);
      acc += __shfl_xor(acc, 4);
      acc += __shfl_xor(acc, 8);
      if (gl == 0) logits[j] = acc;
    }
    __syncthreads();
    float lv[4];
    float m = -INFINITY;
#pragma unroll
    for (int k = 0; k < 4; ++k) {
      lv[k] = logits[tid + 256 * k];
      m = fmaxf(m, lv[k]);
      out_logits[(size_t)i * BB + tid + 256 * k] = lv[k];
    }
    m = waveReduceMax(m);
    if (lane == 0) red[wid] = m;
    __syncthreads();
    float M = fmaxf(fmaxf(red[0], red[1]), fmaxf(red[2], red[3]));
    float s = 0.f;
#pragma unroll
    for (int k = 0; k < 4; ++k) s += expf(lv[k] - M);
    s = waveReduceSum(s);
    if (lane == 0) red[4 + wid] = s;
    __syncthreads();
    float S = red[4] + red[5] + red[6] + red[7];
    float lse = M + logf(S);
    float gmx_i = gm_max[i];
    float inv_i = 1.0f / gm_den[i];
    float c = 0.f;
#pragma unroll
    for (int k = 0; k < 4; ++k) {
      int j = tid + 256 * k;
      float lp = lv[k] - lse;
      float wij = expf(gm[(size_t)i * BB + j] - gmx_i) * inv_i;
      float wji = expf(gm[(size_t)j * BB + i] - gm_max[j]) / gm_den[j];
      c += (wij + wji) * lp;
    }
    c = waveReduceSum(c);
    __syncthreads();
    if (lane == 0) red[wid] = c;
    __syncthreads();
    if (tid == 0) graph_partial[i] = red[0] + red[1] + red[2] + red[3];
  }
}

// K3 pairwise stream: persistent grid-stride (4096 blocks), one ALIGNED
// cached float4 store per iteration. Identical gather + store mode to R5;
// ONLY the launch structure changed (isolates dispatch overhead).
// Region element e: r = e>>8, c = e&255;
//   val = c<128 ? nen[(r>>10)*128+c] : nen[(r&1023)*128+c-128]
// out_pair absolute float offset == 3 (mod 4) so e = 1+4k is 16B-aligned.
#define NF4 67108863UL
__global__ __launch_bounds__(256) void pairwise_kernel(
    const float* __restrict__ nen, float* __restrict__ outp) {
  size_t gid = (size_t)blockIdx.x * 256 + threadIdx.x;
  size_t T = (size_t)gridDim.x * 256;
  for (size_t k = gid; k < NF4; k += T) {
    size_t e0 = 1 + 4 * k;
    floatx4 v;
#pragma unroll
    for (int kk = 0; kk < 4; ++kk) {
      size_t e = e0 + kk;
      int r = (int)(e >> 8);
      int c = (int)(e & 255);
      int row = (c < 128) ? (r >> 10) : (r & 1023);
      int col = c & 127;
      v[kk] = nen[(size_t)row * DD + col];
    }
    *(floatx4*)(outp + e0) = v;  // aligned 16B cached store
  }
  if (gid == 0) {
    outp[0] = nen[0];  // head: e=0 -> row 0, col 0
    // tail: e = 2^28-3 .. 2^28-1 -> r = 1048575 (j=1023), c = 253..255
    outp[268435453UL] = nen[1023 * DD + 125];
    outp[268435454UL] = nen[1023 * DD + 126];
    outp[268435455UL] = nen[1023 * DD + 127];
  }
}

// K4: deterministic final reduce of the 1024-element partial arrays.
__global__ __launch_bounds__(256) void final_kernel(
    const float* __restrict__ node_partial,
    const float* __restrict__ graph_partial, float* __restrict__ out) {
  int tid = threadIdx.x;
  int lane = tid & 63, wid = tid >> 6;
  __shared__ float red[8];
  float ns = 0.f, gs = 0.f;
#pragma unroll
  for (int k = 0; k < 4; ++k) {
    ns += node_partial[tid + 256 * k];
    gs += graph_partial[tid + 256 * k];
  }
  ns = waveReduceSum(ns);
  gs = waveReduceSum(gs);
  if (lane == 0) { red[wid] = ns; red[4 + wid] = gs; }
  __syncthreads();
  if (tid == 0) {
    float nsum = red[0] + red[1] + red[2] + red[3];
    float gsum = red[4] + red[5] + red[6] + red[7];
    float node_loss = -nsum / (float)NN;
    float graph_loss = -gsum / (float)BB;
    float loss = 0.5f * node_loss + 0.5f * graph_loss;
    out[0] = loss;
    out[1] = node_loss;
    out[2] = graph_loss;
  }
}

extern "C" void kernel_launch(void* const* d_in, const int* in_sizes, int n_in,
                              void* d_out, int out_size, void* d_ws,
                              size_t ws_size, hipStream_t stream) {
  const float* ne = (const float*)d_in[0];   // [1024,128]
  const float* ge = (const float*)d_in[1];   // [1024,128]
  const float* gm = (const float*)d_in[2];   // [1024,1024]
  float* out = (float*)d_out;
  float* ws = (float*)d_ws;

  float* ne_n = ws;                    // 131072
  float* ge_n = ws + 131072;           // 131072
  float* gm_max = ws + 262144;         // 1024
  float* gm_den = ws + 263168;         // 1024
  float* node_partial = ws + 264192;   // 1024
  float* graph_partial = ws + 265216;  // 1024

  float* out_logits = out + 3;                       // [1024,1024]
  float* out_pair = out + 3 + (size_t)NN * NN;       // [1024*1024, 256]

  hipLaunchKernelGGL(prep_kernel, dim3(NN + 2 * BB), dim3(64), 0, stream,
                     ne, ge, gm, ne_n, ge_n, gm_max, gm_den);
  hipLaunchKernelGGL(loss_kernel, dim3(2048), dim3(256), 0, stream,
                     ne_n, ge_n, gm, gm_max, gm_den, out_logits,
                     node_partial, graph_partial);
  hipLaunchKernelGGL(pairwise_kernel, dim3(4096), dim3(256), 0, stream,
                     ne_n, out_pair);
  hipLaunchKernelGGL(final_kernel, dim3(1), dim3(256), 0, stream,
                     node_partial, graph_partial, out);
}

// Round 7
// 360.210 us; speedup vs baseline: 1.0760x; 1.0760x over previous
//
#include <hip/hip_runtime.h>
#include <math.h>

#define NN 1024   // nodes
#define DD 128    // dim
#define BB 1024   // graphs
#define TI 32     // i-tile
#define TJ 32     // j-tile

typedef float floatx4 __attribute__((ext_vector_type(4)));

__device__ __forceinline__ float waveReduceSum(float v) {
#pragma unroll
  for (int off = 32; off > 0; off >>= 1) v += __shfl_xor(v, off);
  return v;
}
__device__ __forceinline__ float waveReduceMax(float v) {
#pragma unroll
  for (int off = 32; off > 0; off >>= 1) v = fmaxf(v, __shfl_xor(v, off));
  return v;
}

// K1 prep: blocks 0..NN-1 normalize node rows, NN..NN+BB-1 normalize graph
// rows, NN+BB..NN+2*BB-1 compute gm row max/denominator. 64 threads/block.
__global__ __launch_bounds__(64) void prep_kernel(
    const float* __restrict__ ne, const float* __restrict__ ge,
    const float* __restrict__ gm, float* __restrict__ ne_n,
    float* __restrict__ ge_n, float* __restrict__ gm_max,
    float* __restrict__ gm_den) {
  int b = blockIdx.x;
  int lane = threadIdx.x;
  if (b < NN + BB) {
    const float* src;
    float* dst;
    if (b < NN) { src = ne + (size_t)b * DD; dst = ne_n + (size_t)b * DD; }
    else { src = ge + (size_t)(b - NN) * DD; dst = ge_n + (size_t)(b - NN) * DD; }
    float2 v = ((const float2*)src)[lane];
    float ss = v.x * v.x + v.y * v.y;
    ss = waveReduceSum(ss);
    float scale = 1.0f / fmaxf(sqrtf(ss), 1e-12f);
    float2 o;
    o.x = v.x * scale;
    o.y = v.y * scale;
    ((float2*)dst)[lane] = o;
  } else {
    int row = b - (NN + BB);
    const float4* r = (const float4*)(gm + (size_t)row * BB);
    float vals[16];
    float m = -INFINITY;
#pragma unroll
    for (int k = 0; k < 4; ++k) {
      float4 v = r[lane + 64 * k];
      vals[k * 4 + 0] = v.x; vals[k * 4 + 1] = v.y;
      vals[k * 4 + 2] = v.z; vals[k * 4 + 3] = v.w;
      m = fmaxf(m, fmaxf(fmaxf(v.x, v.y), fmaxf(v.z, v.w)));
    }
    m = waveReduceMax(m);
    float s = 0.f;
#pragma unroll
    for (int t = 0; t < 16; ++t) s += expf(vals[t] - m);
    s = waveReduceSum(s);
    if (lane == 0) { gm_max[row] = m; gm_den[row] = s; }
  }
}

// K2 loss: blocks 0..1023 node-loss rows; 1024..2047 graph-loss rows
// (+ graph_logits store). 16-lane group per j-row dot product.
__global__ __launch_bounds__(256) void loss_kernel(
    const float* __restrict__ nen, const float* __restrict__ gen,
    const float* __restrict__ gm, const float* __restrict__ gm_max,
    const float* __restrict__ gm_den, float* __restrict__ out_logits,
    float* __restrict__ node_partial, float* __restrict__ graph_partial) {
  int bid = blockIdx.x;
  int tid = threadIdx.x;
  int lane = tid & 63, wid = tid >> 6;
  int g = lane >> 4, gl = lane & 15;
  __shared__ float q[DD];
  __shared__ float logits[NN];
  __shared__ float red[8];

  if (bid < 1024) {
    int i = bid;
    if (tid < DD) q[tid] = nen[(size_t)i * DD + tid];
    __syncthreads();
    const float4* qv = (const float4*)q;
    float4 b0 = qv[gl * 2], b1 = qv[gl * 2 + 1];
#pragma unroll 4
    for (int p = 0; p < 64; ++p) {
      int j = p * 16 + wid * 4 + g;
      const float4* rowp = (const float4*)(nen + (size_t)j * DD);
      float4 a0 = rowp[gl * 2], a1 = rowp[gl * 2 + 1];
      float acc = a0.x * b0.x + a0.y * b0.y + a0.z * b0.z + a0.w * b0.w +
                  a1.x * b1.x + a1.y * b1.y + a1.z * b1.z + a1.w * b1.w;
      acc += __shfl_xor(acc, 1);
      acc += __shfl_xor(acc, 2);
      acc += __shfl_xor(acc, 4);
      acc += __shfl_xor(acc, 8);
      if (gl == 0) logits[j] = acc;
    }
    __syncthreads();
    float lv[4];
    float m = -INFINITY;
#pragma unroll
    for (int k = 0; k < 4; ++k) {
      lv[k] = logits[tid + 256 * k];
      m = fmaxf(m, lv[k]);
    }
    m = waveReduceMax(m);
    if (lane == 0) red[wid] = m;
    __syncthreads();
    float M = fmaxf(fmaxf(red[0], red[1]), fmaxf(red[2], red[3]));
    float s = 0.f;
#pragma unroll
    for (int k = 0; k < 4; ++k) s += expf(lv[k] - M);
    s = waveReduceSum(s);
    if (lane == 0) red[4 + wid] = s;
    __syncthreads();
    float S = red[4] + red[5] + red[6] + red[7];
    if (tid == 0) node_partial[i] = logits[i] - (M + logf(S));
  } else {
    // graph loss row i. logits matrix symmetric (bitwise: same reduction
    // order) so lpT == lp; fold both loss terms into one weighted sum.
    int i = bid - 1024;
    if (tid < DD) q[tid] = gen[(size_t)i * DD + tid];
    __syncthreads();
    const float4* qv = (const float4*)q;
    float4 b0 = qv[gl * 2], b1 = qv[gl * 2 + 1];
#pragma unroll 4
    for (int p = 0; p < 64; ++p) {
      int j = p * 16 + wid * 4 + g;
      const float4* rowp = (const float4*)(gen + (size_t)j * DD);
      float4 a0 = rowp[gl * 2], a1 = rowp[gl * 2 + 1];
      float acc = a0.x * b0.x + a0.y * b0.y + a0.z * b0.z + a0.w * b0.w +
                  a1.x * b1.x + a1.y * b1.y + a1.z * b1.z + a1.w * b1.w;
      acc += __shfl_xor(acc, 1);
      acc += __shfl_xor(acc, 2);
      acc += __shfl_xor(acc, 4);
      acc += __shfl_xor(acc, 8);
      if (gl == 0) logits[j] = acc;
    }
    __syncthreads();
    float lv[4];
    float m = -INFINITY;
#pragma unroll
    for (int k = 0; k < 4; ++k) {
      lv[k] = logits[tid + 256 * k];
      m = fmaxf(m, lv[k]);
      out_logits[(size_t)i * BB + tid + 256 * k] = lv[k];
    }
    m = waveReduceMax(m);
    if (lane == 0) red[wid] = m;
    __syncthreads();
    float M = fmaxf(fmaxf(red[0], red[1]), fmaxf(red[2], red[3]));
    float s = 0.f;
#pragma unroll
    for (int k = 0; k < 4; ++k) s += expf(lv[k] - M);
    s = waveReduceSum(s);
    if (lane == 0) red[4 + wid] = s;
    __syncthreads();
    float S = red[4] + red[5] + red[6] + red[7];
    float lse = M + logf(S);
    float gmx_i = gm_max[i];
    float inv_i = 1.0f / gm_den[i];
    float c = 0.f;
#pragma unroll
    for (int k = 0; k < 4; ++k) {
      int j = tid + 256 * k;
      float lp = lv[k] - lse;
      float wij = expf(gm[(size_t)i * BB + j] - gmx_i) * inv_i;
      float wji = expf(gm[(size_t)j * BB + i] - gm_max[j]) / gm_den[j];
      c += (wij + wji) * lp;
    }
    c = waveReduceSum(c);
    __syncthreads();
    if (lane == 0) red[wid] = c;
    __syncthreads();
    if (tid == 0) graph_partial[i] = red[0] + red[1] + red[2] + red[3];
  }
}

// K3 pairwise stream, TILED: block (bi,bj) owns i in [32bi,32bi+32),
// j in [32bj,32bj+32). Stages the 64 needed rows (32 KB) into LDS once,
// then writes its 1 MB of output purely from LDS -> gathers never touch
// L2/HBM (stores were evicting ne_n and doubling HBM traffic).
// Alignment: out_pair absolute float offset == 3 (mod 4), so slots
// e0 = seg+1+4s are 16B-aligned; each chunk (one i, 8192 floats) covers
// e in (seg0, seg0+8192] via 2048 slots; the straddling 4th element at
// x==8192 is fetched by one scalar global gather. Head e=0 by block 0;
// final 3 floats stored scalar.
__global__ __launch_bounds__(512) void pairwise_kernel(
    const float* __restrict__ nen, float* __restrict__ outp) {
  int b = blockIdx.x;
  int bi = b >> 5, bj = b & 31;
  int I0 = bi * TI, J0 = bj * TJ;
  int tid = threadIdx.x;
  __shared__ float lds_i[TI][DD];
  __shared__ float lds_j[TJ][DD];
#pragma unroll
  for (int p = 0; p < 4; ++p) {
    int idx = tid + 512 * p;  // 0..2047 => 64 rows x 32 float4
    int row = idx >> 5;
    int c4 = idx & 31;
    const float* gsrc = (row < TI) ? (nen + (size_t)(I0 + row) * DD)
                                   : (nen + (size_t)(J0 + row - TI) * DD);
    floatx4 v = *(const floatx4*)(gsrc + c4 * 4);
    float* d = (row < TI) ? &lds_i[row][c4 * 4] : &lds_j[row - TI][c4 * 4];
    *(floatx4*)d = v;
  }
  __syncthreads();

  for (int ic = 0; ic < TI; ++ic) {
    size_t seg0 = ((size_t)(I0 + ic) * 1024 + (size_t)J0) * 256;
#pragma unroll
    for (int q = 0; q < 4; ++q) {
      int s = tid + 512 * q;      // 0..2047
      int x0 = 1 + 4 * s;         // 1..8189
      size_t e0 = seg0 + (size_t)x0;
      floatx4 v;
#pragma unroll
      for (int kk = 0; kk < 3; ++kk) {
        int x = x0 + kk;
        int rl = x >> 8, c = x & 255;
        v[kk] = (c < 128) ? lds_i[ic][c] : lds_j[rl][c - 128];
      }
      int x3 = x0 + 3;
      if (x3 <= 8191) {
        int rl = x3 >> 8, c = x3 & 255;
        v[3] = (c < 128) ? lds_i[ic][c] : lds_j[rl][c - 128];
        *(floatx4*)(outp + e0) = v;
      } else {
        // x3 == 8192: boundary element e_b = seg0 + 8192 (c == 0 there)
        size_t eb = seg0 + 8192;
        if (eb < ((size_t)1 << 28)) {
          size_t r = eb >> 8;
          v[3] = nen[(r >> 10) * DD];  // general gather, c=0 -> i-half
          *(floatx4*)(outp + e0) = v;
        } else {
          // very last slot of the buffer: only 3 floats remain
          outp[e0] = v[0];
          outp[e0 + 1] = v[1];
          outp[e0 + 2] = v[2];
        }
      }
    }
  }
  if (b == 0 && tid == 0) outp[0] = nen[0];  // head element e=0
}

// K4: deterministic final reduce of the 1024-element partial arrays.
__global__ __launch_bounds__(256) void final_kernel(
    const float* __restrict__ node_partial,
    const float* __restrict__ graph_partial, float* __restrict__ out) {
  int tid = threadIdx.x;
  int lane = tid & 63, wid = tid >> 6;
  __shared__ float red[8];
  float ns = 0.f, gs = 0.f;
#pragma unroll
  for (int k = 0; k < 4; ++k) {
    ns += node_partial[tid + 256 * k];
    gs += graph_partial[tid + 256 * k];
  }
  ns = waveReduceSum(ns);
  gs = waveReduceSum(gs);
  if (lane == 0) { red[wid] = ns; red[4 + wid] = gs; }
  __syncthreads();
  if (tid == 0) {
    float nsum = red[0] + red[1] + red[2] + red[3];
    float gsum = red[4] + red[5] + red[6] + red[7];
    float node_loss = -nsum / (float)NN;
    float graph_loss = -gsum / (float)BB;
    float loss = 0.5f * node_loss + 0.5f * graph_loss;
    out[0] = loss;
    out[1] = node_loss;
    out[2] = graph_loss;
  }
}

extern "C" void kernel_launch(void* const* d_in, const int* in_sizes, int n_in,
                              void* d_out, int out_size, void* d_ws,
                              size_t ws_size, hipStream_t stream) {
  const float* ne = (const float*)d_in[0];   // [1024,128]
  const float* ge = (const float*)d_in[1];   // [1024,128]
  const float* gm = (const float*)d_in[2];   // [1024,1024]
  float* out = (float*)d_out;
  float* ws = (float*)d_ws;

  float* ne_n = ws;                    // 131072
  float* ge_n = ws + 131072;           // 131072
  float* gm_max = ws + 262144;         // 1024
  float* gm_den = ws + 263168;         // 1024
  float* node_partial = ws + 264192;   // 1024
  float* graph_partial = ws + 265216;  // 1024

  float* out_logits = out + 3;                       // [1024,1024]
  float* out_pair = out + 3 + (size_t)NN * NN;       // [1024*1024, 256]

  hipLaunchKernelGGL(prep_kernel, dim3(NN + 2 * BB), dim3(64), 0, stream,
                     ne, ge, gm, ne_n, ge_n, gm_max, gm_den);
  hipLaunchKernelGGL(loss_kernel, dim3(2048), dim3(256), 0, stream,
                     ne_n, ge_n, gm, gm_max, gm_den, out_logits,
                     node_partial, graph_partial);
  hipLaunchKernelGGL(pairwise_kernel, dim3(1024), dim3(512), 0, stream,
                     ne_n, out_pair);
  hipLaunchKernelGGL(final_kernel, dim3(1), dim3(256), 0, stream,
                     node_partial, graph_partial, out);
}

// Round 9
// 271.554 us; speedup vs baseline: 1.4272x; 1.3265x over previous
//
#include <hip/hip_runtime.h>
#include <math.h>

#define NN 1024   // nodes
#define DD 128    // dim
#define BB 1024   // graphs
#define TI 8      // i-rows per block
#define TJ 32     // j-rows per block

typedef float floatx4 __attribute__((ext_vector_type(4)));

__device__ __forceinline__ float waveReduceSum(float v) {
#pragma unroll
  for (int off = 32; off > 0; off >>= 1) v += __shfl_xor(v, off);
  return v;
}
__device__ __forceinline__ float waveReduceMax(float v) {
#pragma unroll
  for (int off = 32; off > 0; off >>= 1) v = fmaxf(v, __shfl_xor(v, off));
  return v;
}

// K1 prep: blocks 0..NN-1 normalize node rows, NN..NN+BB-1 normalize graph
// rows, NN+BB..NN+2*BB-1 compute gm row max/denominator. 64 threads/block.
__global__ __launch_bounds__(64) void prep_kernel(
    const float* __restrict__ ne, const float* __restrict__ ge,
    const float* __restrict__ gm, float* __restrict__ ne_n,
    float* __restrict__ ge_n, float* __restrict__ gm_max,
    float* __restrict__ gm_den) {
  int b = blockIdx.x;
  int lane = threadIdx.x;
  if (b < NN + BB) {
    const float* src;
    float* dst;
    if (b < NN) { src = ne + (size_t)b * DD; dst = ne_n + (size_t)b * DD; }
    else { src = ge + (size_t)(b - NN) * DD; dst = ge_n + (size_t)(b - NN) * DD; }
    float2 v = ((const float2*)src)[lane];
    float ss = v.x * v.x + v.y * v.y;
    ss = waveReduceSum(ss);
    float scale = 1.0f / fmaxf(sqrtf(ss), 1e-12f);
    float2 o;
    o.x = v.x * scale;
    o.y = v.y * scale;
    ((float2*)dst)[lane] = o;
  } else {
    int row = b - (NN + BB);
    const float4* r = (const float4*)(gm + (size_t)row * BB);
    float vals[16];
    float m = -INFINITY;
#pragma unroll
    for (int k = 0; k < 4; ++k) {
      float4 v = r[lane + 64 * k];
      vals[k * 4 + 0] = v.x; vals[k * 4 + 1] = v.y;
      vals[k * 4 + 2] = v.z; vals[k * 4 + 3] = v.w;
      m = fmaxf(m, fmaxf(fmaxf(v.x, v.y), fmaxf(v.z, v.w)));
    }
    m = waveReduceMax(m);
    float s = 0.f;
#pragma unroll
    for (int t = 0; t < 16; ++t) s += expf(vals[t] - m);
    s = waveReduceSum(s);
    if (lane == 0) { gm_max[row] = m; gm_den[row] = s; }
  }
}

// K2 loss: blocks 0..1023 node-loss rows; 1024..2047 graph-loss rows
// (+ graph_logits store). 16-lane group per j-row dot product.
__global__ __launch_bounds__(256) void loss_kernel(
    const float* __restrict__ nen, const float* __restrict__ gen,
    const float* __restrict__ gm, const float* __restrict__ gm_max,
    const float* __restrict__ gm_den, float* __restrict__ out_logits,
    float* __restrict__ node_partial, float* __restrict__ graph_partial) {
  int bid = blockIdx.x;
  int tid = threadIdx.x;
  int lane = tid & 63, wid = tid >> 6;
  int g = lane >> 4, gl = lane & 15;
  __shared__ float q[DD];
  __shared__ float logits[NN];
  __shared__ float red[8];

  if (bid < 1024) {
    int i = bid;
    if (tid < DD) q[tid] = nen[(size_t)i * DD + tid];
    __syncthreads();
    const float4* qv = (const float4*)q;
    float4 b0 = qv[gl * 2], b1 = qv[gl * 2 + 1];
#pragma unroll 4
    for (int p = 0; p < 64; ++p) {
      int j = p * 16 + wid * 4 + g;
      const float4* rowp = (const float4*)(nen + (size_t)j * DD);
      float4 a0 = rowp[gl * 2], a1 = rowp[gl * 2 + 1];
      float acc = a0.x * b0.x + a0.y * b0.y + a0.z * b0.z + a0.w * b0.w +
                  a1.x * b1.x + a1.y * b1.y + a1.z * b1.z + a1.w * b1.w;
      acc += __shfl_xor(acc, 1);
      acc += __shfl_xor(acc, 2);
      acc += __shfl_xor(acc, 4);
      acc += __shfl_xor(acc, 8);
      if (gl == 0) logits[j] = acc;
    }
    __syncthreads();
    float lv[4];
    float m = -INFINITY;
#pragma unroll
    for (int k = 0; k < 4; ++k) {
      lv[k] = logits[tid + 256 * k];
      m = fmaxf(m, lv[k]);
    }
    m = waveReduceMax(m);
    if (lane == 0) red[wid] = m;
    __syncthreads();
    float M = fmaxf(fmaxf(red[0], red[1]), fmaxf(red[2], red[3]));
    float s = 0.f;
#pragma unroll
    for (int k = 0; k < 4; ++k) s += expf(lv[k] - M);
    s = waveReduceSum(s);
    if (lane == 0) red[4 + wid] = s;
    __syncthreads();
    float S = red[4] + red[5] + red[6] + red[7];
    if (tid == 0) node_partial[i] = logits[i] - (M + logf(S));
  } else {
    // graph loss row i. logits matrix symmetric (bitwise: same reduction
    // order) so lpT == lp; fold both loss terms into one weighted sum.
    int i = bid - 1024;
    if (tid < DD) q[tid] = gen[(size_t)i * DD + tid];
    __syncthreads();
    const float4* qv = (const float4*)q;
    float4 b0 = qv[gl * 2], b1 = qv[gl * 2 + 1];
#pragma unroll 4
    for (int p = 0; p < 64; ++p) {
      int j = p * 16 + wid * 4 + g;
      const float4* rowp = (const float4*)(gen + (size_t)j * DD);
      float4 a0 = rowp[gl * 2], a1 = rowp[gl * 2 + 1];
      float acc = a0.x * b0.x + a0.y * b0.y + a0.z * b0.z + a0.w * b0.w +
                  a1.x * b1.x + a1.y * b1.y + a1.z * b1.z + a1.w * b1.w;
      acc += __shfl_xor(acc, 1);
      acc += __shfl_xor(acc, 2);
      acc += __shfl_xor(acc, 4);
      acc += __shfl_xor(acc, 8);
      if (gl == 0) logits[j] = acc;
    }
    __syncthreads();
    float lv[4];
    float m = -INFINITY;
#pragma unroll
    for (int k = 0; k < 4; ++k) {
      lv[k] = logits[tid + 256 * k];
      m = fmaxf(m, lv[k]);
      out_logits[(size_t)i * BB + tid + 256 * k] = lv[k];
    }
    m = waveReduceMax(m);
    if (lane == 0) red[wid] = m;
    __syncthreads();
    float M = fmaxf(fmaxf(red[0], red[1]), fmaxf(red[2], red[3]));
    float s = 0.f;
#pragma unroll
    for (int k = 0; k < 4; ++k) s += expf(lv[k] - M);
    s = waveReduceSum(s);
    if (lane == 0) red[4 + wid] = s;
    __syncthreads();
    float S = red[4] + red[5] + red[6] + red[7];
    float lse = M + logf(S);
    float gmx_i = gm_max[i];
    float inv_i = 1.0f / gm_den[i];
    float c = 0.f;
#pragma unroll
    for (int k = 0; k < 4; ++k) {
      int j = tid + 256 * k;
      float lp = lv[k] - lse;
      float wij = expf(gm[(size_t)i * BB + j] - gmx_i) * inv_i;
      float wji = expf(gm[(size_t)j * BB + i] - gm_max[j]) / gm_den[j];
      c += (wij + wji) * lp;
    }
    c = waveReduceSum(c);
    __syncthreads();
    if (lane == 0) red[wid] = c;
    __syncthreads();
    if (tid == 0) graph_partial[i] = red[0] + red[1] + red[2] + red[3];
  }
}

// K3 pairwise stream, tiled + PRE-SHIFTED LDS.
// Block (bi,bj): i in [8bi,8bi+8), j in [32bj,32bj+32). LDS holds rows
// shifted by +1 float (SH*[x] = row[x+1]) so each output slot
// e0 = seg+1+4S (16B-aligned globally, since region base == 3 mod 4)
// maps to ONE aligned ds_read_b128; lanes 31/63 patch v.w via cndmask.
// Patch value derivation (output position crossing):
//   lane31 (c=125..128): 4th elem = ne[jc][0]           -> lj0
//   lane63 (c=253..256): 4th elem = first elem of NEXT output row:
//     jc<31  -> next row (i, j+1) starts with ne[i][0]  -> li0
//     jc==31 (w==3 && q==7):
//       bj<31 -> next segment (i, J0+32) elem0 = ne[i][0] -> li0
//       bj==31-> next segment (i+1, 0) elem0 = ne[i+1][0] -> li0n
// R8 bug: condition used q==7 alone; lane63 exists at w=0..3, so jc was
// 28..30 for w<3 and got li0n wrongly. Fixed: (bj31 && w==3 && q==7).
__global__ __launch_bounds__(256) void pairwise_kernel(
    const float* __restrict__ nen, float* __restrict__ outp) {
  int b = blockIdx.x;
  int bi = b >> 5, bj = b & 31;
  int I0 = bi * TI, J0 = bj * TJ;
  int tid = threadIdx.x;
  int lane = tid & 63;
  int w = tid >> 6;

  __shared__ float SHI[TI][DD];   // SHI[ic][x] = nen[I0+ic][x+1] (x<127)
  __shared__ float SHJ[TJ][DD];   // SHJ[jc][x] = nen[J0+jc][x+1] (x<127)
  __shared__ float LJ0[TJ];       // nen[J0+jc][0]
  __shared__ float LI0[TI];       // nen[I0+ic][0]
  __shared__ float LI0N[TI];      // nen[I0+ic+1][0] (clamped at end)

  // stage 40 rows x 32 float4 slots = 1280 tasks, 5 per thread.
#pragma unroll
  for (int p = 0; p < 5; ++p) {
    int task = tid + 256 * p;   // 0..1279
    int row = task >> 5;        // 0..39
    int c4 = task & 31;
    const float* src = (row < TI) ? nen + (size_t)(I0 + row) * DD
                                  : nen + (size_t)(J0 + row - TI) * DD;
    floatx4 A = *(const floatx4*)(src + 4 * c4);
    float nxt = __shfl_down(A.x, 1);  // c4==31 lanes produce pad (unused)
    floatx4 Sv;
    Sv.x = A.y; Sv.y = A.z; Sv.z = A.w; Sv.w = nxt;
    float* dst = (row < TI) ? &SHI[row][4 * c4] : &SHJ[row - TI][4 * c4];
    *(floatx4*)dst = Sv;
    if (c4 == 0) {
      if (row < TI) {
        LI0[row] = A.x;
        int nr = I0 + row + 1;
        if (nr > 1023) nr = 0;      // value unused (global tail)
        LI0N[row] = nen[(size_t)nr * DD];
      } else {
        LJ0[row - TI] = A.x;
      }
    }
  }
  __syncthreads();

  bool is31 = (lane == 31);
  bool is63 = (lane == 63);
  bool patch = is31 | is63;
  bool lastSeg = (bj == 31) && (w == 3);  // with q==7 -> jc==31 at bj 31
  bool tailThread = (b == 4095) && (tid == 255);

  for (int ic = 0; ic < TI; ++ic) {
    float li0 = LI0[ic];
    float li0n = LI0N[ic];
    size_t segf = (((size_t)(I0 + ic) << 10) + (size_t)J0) << 8;
    float* gb = outp + segf + 1 + 4 * tid;
#pragma unroll
    for (int q = 0; q < 8; ++q) {
      int jc = w + 4 * q;  // wave-uniform
      const float* addr = (lane < 32) ? &SHI[ic][4 * lane]
                                      : &SHJ[jc][4 * (lane - 32)];
      floatx4 v = *(const floatx4*)addr;
      float lj0 = LJ0[jc];  // broadcast
      float spec = is31 ? lj0 : ((lastSeg && q == 7) ? li0n : li0);
      v.w = patch ? spec : v.w;
      if (tailThread && ic == TI - 1 && q == 7) {
        gb[0] = v.x; gb[1] = v.y; gb[2] = v.z;  // e = 2^28-3..2^28-1
      } else {
        *(floatx4*)gb = v;
      }
      gb += 1024;
    }
  }
  if (b == 0 && tid == 0) outp[0] = nen[0];  // head element e=0
}

// K4: deterministic final reduce of the 1024-element partial arrays.
__global__ __launch_bounds__(256) void final_kernel(
    const float* __restrict__ node_partial,
    const float* __restrict__ graph_partial, float* __restrict__ out) {
  int tid = threadIdx.x;
  int lane = tid & 63, wid = tid >> 6;
  __shared__ float red[8];
  float ns = 0.f, gs = 0.f;
#pragma unroll
  for (int k = 0; k < 4; ++k) {
    ns += node_partial[tid + 256 * k];
    gs += graph_partial[tid + 256 * k];
  }
  ns = waveReduceSum(ns);
  gs = waveReduceSum(gs);
  if (lane == 0) { red[wid] = ns; red[4 + wid] = gs; }
  __syncthreads();
  if (tid == 0) {
    float nsum = red[0] + red[1] + red[2] + red[3];
    float gsum = red[4] + red[5] + red[6] + red[7];
    float node_loss = -nsum / (float)NN;
    float graph_loss = -gsum / (float)BB;
    float loss = 0.5f * node_loss + 0.5f * graph_loss;
    out[0] = loss;
    out[1] = node_loss;
    out[2] = graph_loss;
  }
}

extern "C" void kernel_launch(void* const* d_in, const int* in_sizes, int n_in,
                              void* d_out, int out_size, void* d_ws,
                              size_t ws_size, hipStream_t stream) {
  const float* ne = (const float*)d_in[0];   // [1024,128]
  const float* ge = (const float*)d_in[1];   // [1024,128]
  const float* gm = (const float*)d_in[2];   // [1024,1024]
  float* out = (float*)d_out;
  float* ws = (float*)d_ws;

  float* ne_n = ws;                    // 131072
  float* ge_n = ws + 131072;           // 131072
  float* gm_max = ws + 262144;         // 1024
  float* gm_den = ws + 263168;         // 1024
  float* node_partial = ws + 264192;   // 1024
  float* graph_partial = ws + 265216;  // 1024

  float* out_logits = out + 3;                       // [1024,1024]
  float* out_pair = out + 3 + (size_t)NN * NN;       // [1024*1024, 256]

  hipLaunchKernelGGL(prep_kernel, dim3(NN + 2 * BB), dim3(64), 0, stream,
                     ne, ge, gm, ne_n, ge_n, gm_max, gm_den);
  hipLaunchKernelGGL(loss_kernel, dim3(2048), dim3(256), 0, stream,
                     ne_n, ge_n, gm, gm_max, gm_den, out_logits,
                     node_partial, graph_partial);
  hipLaunchKernelGGL(pairwise_kernel, dim3(4096), dim3(256), 0, stream,
                     ne_n, out_pair);
  hipLaunchKernelGGL(final_kernel, dim3(1), dim3(256), 0, stream,
                     node_partial, graph_partial, out);
}

// Round 10
// 242.295 us; speedup vs baseline: 1.5996x; 1.1208x over previous
//
#include <hip/hip_runtime.h>
#include <math.h>

#define NN 1024   // nodes
#define DD 128    // dim
#define BB 1024   // graphs
#define TI 8      // i-rows per pairwise block
#define TJ 32     // j-rows per pairwise block

typedef float floatx4 __attribute__((ext_vector_type(4)));

__device__ __forceinline__ float waveReduceSum(float v) {
#pragma unroll
  for (int off = 32; off > 0; off >>= 1) v += __shfl_xor(v, off);
  return v;
}
__device__ __forceinline__ float waveReduceMax(float v) {
#pragma unroll
  for (int off = 32; off > 0; off >>= 1) v = fmaxf(v, __shfl_xor(v, off));
  return v;
}

// K1 prep: blocks 0..NN-1 normalize node rows, NN..NN+BB-1 normalize graph
// rows, NN+BB..NN+2*BB-1 compute gm row max/denominator. 64 threads/block.
__global__ __launch_bounds__(64) void prep_kernel(
    const float* __restrict__ ne, const float* __restrict__ ge,
    const float* __restrict__ gm, float* __restrict__ ne_n,
    float* __restrict__ ge_n, float* __restrict__ gm_max,
    float* __restrict__ gm_den) {
  int b = blockIdx.x;
  int lane = threadIdx.x;
  if (b < NN + BB) {
    const float* src;
    float* dst;
    if (b < NN) { src = ne + (size_t)b * DD; dst = ne_n + (size_t)b * DD; }
    else { src = ge + (size_t)(b - NN) * DD; dst = ge_n + (size_t)(b - NN) * DD; }
    float2 v = ((const float2*)src)[lane];
    float ss = v.x * v.x + v.y * v.y;
    ss = waveReduceSum(ss);
    float scale = 1.0f / fmaxf(sqrtf(ss), 1e-12f);
    float2 o;
    o.x = v.x * scale;
    o.y = v.y * scale;
    ((float2*)dst)[lane] = o;
  } else {
    int row = b - (NN + BB);
    const float4* r = (const float4*)(gm + (size_t)row * BB);
    float vals[16];
    float m = -INFINITY;
#pragma unroll
    for (int k = 0; k < 4; ++k) {
      float4 v = r[lane + 64 * k];
      vals[k * 4 + 0] = v.x; vals[k * 4 + 1] = v.y;
      vals[k * 4 + 2] = v.z; vals[k * 4 + 3] = v.w;
      m = fmaxf(m, fmaxf(fmaxf(v.x, v.y), fmaxf(v.z, v.w)));
    }
    m = waveReduceMax(m);
    float s = 0.f;
#pragma unroll
    for (int t = 0; t < 16; ++t) s += expf(vals[t] - m);
    s = waveReduceSum(s);
    if (lane == 0) { gm_max[row] = m; gm_den[row] = s; }
  }
}

// K2 fused: heterogeneous INTERLEAVED grid (6144 blocks).
//   b % 3 == 2 -> loss block   lossId = b/3   (0..2047)
//   else       -> pairwise blk pwId = (b/3)*2 + (b%3)  (0..4095)
// Interleaving keeps ~1/3 compute blocks resident alongside the write
// stream at all times, so loss VALU work hides in the stream's idle
// issue slots (R2's all-loss-first layout just serialized them).
// Shared memory is a union: pairwise needs 20672 B, loss needs 4640 B.
__global__ __launch_bounds__(256) void fused_kernel(
    const float* __restrict__ nen, const float* __restrict__ gen,
    const float* __restrict__ gm, const float* __restrict__ gm_max,
    const float* __restrict__ gm_den, float* __restrict__ out_logits,
    float* __restrict__ outp, float* __restrict__ node_partial,
    float* __restrict__ graph_partial) {
  __shared__ __align__(16) char smem[20672];
  int b = blockIdx.x;
  int tid = threadIdx.x;
  int lane = tid & 63;
  int w = tid >> 6;
  int m3 = b % 3;

  if (m3 != 2) {
    // ---------------- pairwise block ----------------
    int pwId = (b / 3) * 2 + m3;
    int bi = pwId >> 5, bj = pwId & 31;
    int I0 = bi * TI, J0 = bj * TJ;
    float (*SHI)[DD] = (float (*)[DD])smem;                    // 4096 B
    float (*SHJ)[DD] = (float (*)[DD])(smem + 4096);           // 16384 B
    float* LJ0 = (float*)(smem + 20480);                       // 128 B
    float* LI0 = (float*)(smem + 20608);                       // 32 B
    float* LI0N = (float*)(smem + 20640);                      // 32 B

#pragma unroll
    for (int p = 0; p < 5; ++p) {
      int task = tid + 256 * p;   // 0..1279 = 40 rows x 32 float4
      int row = task >> 5;
      int c4 = task & 31;
      const float* src = (row < TI) ? nen + (size_t)(I0 + row) * DD
                                    : nen + (size_t)(J0 + row - TI) * DD;
      floatx4 A = *(const floatx4*)(src + 4 * c4);
      float nxt = __shfl_down(A.x, 1);  // c4==31 lanes: pad (unused)
      floatx4 Sv;
      Sv.x = A.y; Sv.y = A.z; Sv.z = A.w; Sv.w = nxt;
      float* dst = (row < TI) ? &SHI[row][4 * c4] : &SHJ[row - TI][4 * c4];
      *(floatx4*)dst = Sv;
      if (c4 == 0) {
        if (row < TI) {
          LI0[row] = A.x;
          int nr = I0 + row + 1;
          if (nr > 1023) nr = 0;      // value unused (global tail)
          LI0N[row] = nen[(size_t)nr * DD];
        } else {
          LJ0[row - TI] = A.x;
        }
      }
    }
    __syncthreads();

    bool is31 = (lane == 31);
    bool is63 = (lane == 63);
    bool patch = is31 | is63;
    bool lastSeg = (bj == 31) && (w == 3);  // with q==7 -> jc==31
    bool tailThread = (pwId == 4095) && (tid == 255);

    for (int ic = 0; ic < TI; ++ic) {
      float li0 = LI0[ic];
      float li0n = LI0N[ic];
      size_t segf = (((size_t)(I0 + ic) << 10) + (size_t)J0) << 8;
      float* gb = outp + segf + 1 + 4 * tid;
#pragma unroll
      for (int q = 0; q < 8; ++q) {
        int jc = w + 4 * q;  // wave-uniform
        const float* addr = (lane < 32) ? &SHI[ic][4 * lane]
                                        : &SHJ[jc][4 * (lane - 32)];
        floatx4 v = *(const floatx4*)addr;
        float lj0 = LJ0[jc];  // broadcast
        float spec = is31 ? lj0 : ((lastSeg && q == 7) ? li0n : li0);
        v.w = patch ? spec : v.w;
        if (tailThread && ic == TI - 1 && q == 7) {
          gb[0] = v.x; gb[1] = v.y; gb[2] = v.z;  // e = 2^28-3..2^28-1
        } else {
          *(floatx4*)gb = v;
        }
        gb += 1024;
      }
    }
    if (pwId == 0 && tid == 0) outp[0] = nen[0];  // head element e=0
    return;
  }

  // ---------------- loss block ----------------
  int lossId = b / 3;
  float* q = (float*)smem;            // 128 floats
  float* logits = q + DD;             // 1024 floats
  float* red = logits + NN;           // 8 floats
  int g = lane >> 4, gl = lane & 15;

  if (lossId < 1024) {
    int i = lossId;
    if (tid < DD) q[tid] = nen[(size_t)i * DD + tid];
    __syncthreads();
    const float4* qv = (const float4*)q;
    float4 b0 = qv[gl * 2], b1 = qv[gl * 2 + 1];
#pragma unroll 4
    for (int p = 0; p < 64; ++p) {
      int j = p * 16 + w * 4 + g;
      const float4* rowp = (const float4*)(nen + (size_t)j * DD);
      float4 a0 = rowp[gl * 2], a1 = rowp[gl * 2 + 1];
      float acc = a0.x * b0.x + a0.y * b0.y + a0.z * b0.z + a0.w * b0.w +
                  a1.x * b1.x + a1.y * b1.y + a1.z * b1.z + a1.w * b1.w;
      acc += __shfl_xor(acc, 1);
      acc += __shfl_xor(acc, 2);
      acc += __shfl_xor(acc, 4);
      acc += __shfl_xor(acc, 8);
      if (gl == 0) logits[j] = acc;
    }
    __syncthreads();
    float lv[4];
    float m = -INFINITY;
#pragma unroll
    for (int k = 0; k < 4; ++k) {
      lv[k] = logits[tid + 256 * k];
      m = fmaxf(m, lv[k]);
    }
    m = waveReduceMax(m);
    if (lane == 0) red[w] = m;
    __syncthreads();
    float M = fmaxf(fmaxf(red[0], red[1]), fmaxf(red[2], red[3]));
    float s = 0.f;
#pragma unroll
    for (int k = 0; k < 4; ++k) s += expf(lv[k] - M);
    s = waveReduceSum(s);
    if (lane == 0) red[4 + w] = s;
    __syncthreads();
    float S = red[4] + red[5] + red[6] + red[7];
    if (tid == 0) node_partial[i] = logits[i] - (M + logf(S));
  } else {
    // graph loss row i. logits matrix symmetric (bitwise: same reduction
    // order) so lpT == lp; fold both loss terms into one weighted sum.
    int i = lossId - 1024;
    if (tid < DD) q[tid] = gen[(size_t)i * DD + tid];
    __syncthreads();
    const float4* qv = (const float4*)q;
    float4 b0 = qv[gl * 2], b1 = qv[gl * 2 + 1];
#pragma unroll 4
    for (int p = 0; p < 64; ++p) {
      int j = p * 16 + w * 4 + g;
      const float4* rowp = (const float4*)(gen + (size_t)j * DD);
      float4 a0 = rowp[gl * 2], a1 = rowp[gl * 2 + 1];
      float acc = a0.x * b0.x + a0.y * b0.y + a0.z * b0.z + a0.w * b0.w +
                  a1.x * b1.x + a1.y * b1.y + a1.z * b1.z + a1.w * b1.w;
      acc += __shfl_xor(acc, 1);
      acc += __shfl_xor(acc, 2);
      acc += __shfl_xor(acc, 4);
      acc += __shfl_xor(acc, 8);
      if (gl == 0) logits[j] = acc;
    }
    __syncthreads();
    float lv[4];
    float m = -INFINITY;
#pragma unroll
    for (int k = 0; k < 4; ++k) {
      lv[k] = logits[tid + 256 * k];
      m = fmaxf(m, lv[k]);
      out_logits[(size_t)i * BB + tid + 256 * k] = lv[k];
    }
    m = waveReduceMax(m);
    if (lane == 0) red[w] = m;
    __syncthreads();
    float M = fmaxf(fmaxf(red[0], red[1]), fmaxf(red[2], red[3]));
    float s = 0.f;
#pragma unroll
    for (int k = 0; k < 4; ++k) s += expf(lv[k] - M);
    s = waveReduceSum(s);
    if (lane == 0) red[4 + w] = s;
    __syncthreads();
    float S = red[4] + red[5] + red[6] + red[7];
    float lse = M + logf(S);
    float gmx_i = gm_max[i];
    float inv_i = 1.0f / gm_den[i];
    float c = 0.f;
#pragma unroll
    for (int k = 0; k < 4; ++k) {
      int j = tid + 256 * k;
      float lp = lv[k] - lse;
      float wij = expf(gm[(size_t)i * BB + j] - gmx_i) * inv_i;
      float wji = expf(gm[(size_t)j * BB + i] - gm_max[j]) / gm_den[j];
      c += (wij + wji) * lp;
    }
    c = waveReduceSum(c);
    __syncthreads();
    if (lane == 0) red[w] = c;
    __syncthreads();
    if (tid == 0) graph_partial[i] = red[0] + red[1] + red[2] + red[3];
  }
}

// K3: deterministic final reduce of the 1024-element partial arrays.
__global__ __launch_bounds__(256) void final_kernel(
    const float* __restrict__ node_partial,
    const float* __restrict__ graph_partial, float* __restrict__ out) {
  int tid = threadIdx.x;
  int lane = tid & 63, wid = tid >> 6;
  __shared__ float red[8];
  float ns = 0.f, gs = 0.f;
#pragma unroll
  for (int k = 0; k < 4; ++k) {
    ns += node_partial[tid + 256 * k];
    gs += graph_partial[tid + 256 * k];
  }
  ns = waveReduceSum(ns);
  gs = waveReduceSum(gs);
  if (lane == 0) { red[wid] = ns; red[4 + wid] = gs; }
  __syncthreads();
  if (tid == 0) {
    float nsum = red[0] + red[1] + red[2] + red[3];
    float gsum = red[4] + red[5] + red[6] + red[7];
    float node_loss = -nsum / (float)NN;
    float graph_loss = -gsum / (float)BB;
    float loss = 0.5f * node_loss + 0.5f * graph_loss;
    out[0] = loss;
    out[1] = node_loss;
    out[2] = graph_loss;
  }
}

extern "C" void kernel_launch(void* const* d_in, const int* in_sizes, int n_in,
                              void* d_out, int out_size, void* d_ws,
                              size_t ws_size, hipStream_t stream) {
  const float* ne = (const float*)d_in[0];   // [1024,128]
  const float* ge = (const float*)d_in[1];   // [1024,128]
  const float* gm = (const float*)d_in[2];   // [1024,1024]
  float* out = (float*)d_out;
  float* ws = (float*)d_ws;

  float* ne_n = ws;                    // 131072
  float* ge_n = ws + 131072;           // 131072
  float* gm_max = ws + 262144;         // 1024
  float* gm_den = ws + 263168;         // 1024
  float* node_partial = ws + 264192;   // 1024
  float* graph_partial = ws + 265216;  // 1024

  float* out_logits = out + 3;                       // [1024,1024]
  float* out_pair = out + 3 + (size_t)NN * NN;       // [1024*1024, 256]

  hipLaunchKernelGGL(prep_kernel, dim3(NN + 2 * BB), dim3(64), 0, stream,
                     ne, ge, gm, ne_n, ge_n, gm_max, gm_den);
  hipLaunchKernelGGL(fused_kernel, dim3(6144), dim3(256), 0, stream,
                     ne_n, ge_n, gm, gm_max, gm_den, out_logits,
                     out_pair, node_partial, graph_partial);
  hipLaunchKernelGGL(final_kernel, dim3(1), dim3(256), 0, stream,
                     node_partial, graph_partial, out);
}